// Round 1
// 108.235 us; speedup vs baseline: 1.1307x; 1.1307x over previous
//
#include <hip/hip_runtime.h>
#include <hip/hip_bf16.h>

// Problem constants (from reference): B=64, T=8000, S=10.
#define B_ 64
#define T_ 8000
#define S_ 10
#define NCHUNK 8             // T split into 8 chunks of 1000 t's
#define TPC 1000             // t's per chunk
#define QUADS 250            // threads 0..249 each own 4 consecutive t's (160 B)

// ws layout:
//   partial : [B][NCHUNK][112] floats  (110 used: M[100] then D[10])

// ---------------------------------------------------------------------------
// Wave64 sum via DPP (no DS-pipe traffic). Result is valid in lane 63.
// Classic GCN chain: row_shr 1/2/4/8 (prefix within 16-lane rows; lane 15 of
// each row holds the row total), row_bcast15 (row_mask 0xa: odd rows add the
// preceding even row's total -> lanes 31/63 hold 32-lane totals), row_bcast31
// (row_mask 0xc: upper half adds lane 31's 0..31 total -> lane 63 = full sum).
// Each step compiles to one v_add_f32 with a DPP modifier (VALU pipe), vs the
// previous __shfl_xor butterfly = 6 ds_bpermute per value (DS pipe).
// ---------------------------------------------------------------------------
__device__ __forceinline__ float wave64_sum_lane63(float x)
{
    int t;
    t = __builtin_amdgcn_update_dpp(0, __float_as_int(x), 0x111, 0xf, 0xf, true); // row_shr:1
    x += __int_as_float(t);
    t = __builtin_amdgcn_update_dpp(0, __float_as_int(x), 0x112, 0xf, 0xf, true); // row_shr:2
    x += __int_as_float(t);
    t = __builtin_amdgcn_update_dpp(0, __float_as_int(x), 0x114, 0xf, 0xf, true); // row_shr:4
    x += __int_as_float(t);
    t = __builtin_amdgcn_update_dpp(0, __float_as_int(x), 0x118, 0xf, 0xf, true); // row_shr:8
    x += __int_as_float(t);
    t = __builtin_amdgcn_update_dpp(0, __float_as_int(x), 0x142, 0xa, 0xf, true); // row_bcast:15
    x += __int_as_float(t);
    t = __builtin_amdgcn_update_dpp(0, __float_as_int(x), 0x143, 0xc, 0xf, true); // row_bcast:31
    x += __int_as_float(t);
    return x;  // lane 63 holds the 64-lane sum
}

// ---------------------------------------------------------------------------
// Kernel 1: accumulate M[i][j] = sum_t (logp - log1mp)[t,i] * tgt[t,j]
//           and      D[i]     = sum_t log1mp[t,i]
// grid (NCHUNK, B) x 256 threads = 512 blocks = 2 blocks/CU. Thread tid<250
// owns 4 consecutive t's -> 10 contiguous float4 loads per input, issued
// before any compute so all 20 loads stay in flight (memory-bound goal:
// 41 MB read-once at ~6.3 TB/s ~= 6.5 us).
// Epilogue: per-wave DPP reduce (VALU) replaces the ds_bpermute butterfly
// that was serializing ~660 DS ops/wave on the single LDS pipe per CU.
// Also zeroes out[0] (poisoned 0xAA) so kernel 2 can atomicAdd into it.
// ---------------------------------------------------------------------------
__global__ __launch_bounds__(256, 1) void pit_cost_kernel(
    const float* __restrict__ pred, const float* __restrict__ tgt,
    float* __restrict__ partial, float* __restrict__ out)
{
    const int b     = blockIdx.y;
    const int chunk = blockIdx.x;
    const int tid   = threadIdx.x;

    if (b == 0 && chunk == 0 && tid == 0) out[0] = 0.0f;

    float acc[110];
#pragma unroll
    for (int v = 0; v < 110; ++v) acc[v] = 0.0f;

    if (tid < QUADS) {
        const size_t off = (size_t)b * (T_ * S_) + (size_t)chunk * (TPC * S_)
                         + (size_t)tid * 40;
        const float4* P = reinterpret_cast<const float4*>(pred + off);
        const float4* G = reinterpret_cast<const float4*>(tgt + off);
        alignas(16) float pr[40];
        alignas(16) float tg[40];
#pragma unroll
        for (int k = 0; k < 10; ++k) reinterpret_cast<float4*>(pr)[k] = P[k];
#pragma unroll
        for (int k = 0; k < 10; ++k) reinterpret_cast<float4*>(tg)[k] = G[k];

#pragma unroll
        for (int u = 0; u < 4; ++u) {
            float d[10];
#pragma unroll
            for (int i = 0; i < 10; ++i) {
                const float pv = pr[u * 10 + i];
                const float lm = __logf(1.0f - pv);   // log(1-p)
                d[i] = __logf(pv) - lm;               // logit(p)
                acc[100 + i] += lm;                   // D[i]
            }
#pragma unroll
            for (int i = 0; i < 10; ++i) {
#pragma unroll
                for (int j = 0; j < 10; ++j) {
                    acc[i * 10 + j] += d[i] * tg[u * 10 + j];  // M[i][j]
                }
            }
        }
    }

    // Block reduction: per-wave DPP sum (lane 63), then cross-wave sum via LDS.
    __shared__ float red[4][112];
    const int wave = tid >> 6;
    const int lane = tid & 63;
#pragma unroll
    for (int v = 0; v < 110; ++v) {
        const float x = wave64_sum_lane63(acc[v]);
        if (lane == 63) red[wave][v] = x;
    }
    __syncthreads();
    if (tid < 110) {
        const float s = red[0][tid] + red[1][tid] + red[2][tid] + red[3][tid];
        partial[((size_t)b * NCHUNK + chunk) * 112 + tid] = s;
    }
}

// ---------------------------------------------------------------------------
// Kernel 2: per batch b -- finalize cost[i][j] = -(M[i][j] + D[i]) (raw, >0),
// exact min-cost assignment via subset DP over column masks:
//   dp[mask] = min_{j in mask} dp[mask \ j] + cost[popc(mask)-1][j]
// then atomicAdd the normalized optimum into out[0] (zeroed by kernel 1).
// ---------------------------------------------------------------------------
__global__ __launch_bounds__(256, 1) void pit_dp_kernel(
    const float* __restrict__ partial, float* __restrict__ out)
{
    const int b   = blockIdx.x;
    const int tid = threadIdx.x;

    __shared__ float sum[112];
    __shared__ float cost[100];
    __shared__ float dp[1024];

    if (tid < 110) {
        const float* pb = partial + (size_t)b * NCHUNK * 112;
        float s = 0.0f;
#pragma unroll
        for (int c = 0; c < NCHUNK; ++c) s += pb[c * 112 + tid];
        sum[tid] = s;
    }
    __syncthreads();
    if (tid < 100) cost[tid] = -(sum[tid] + sum[100 + tid / 10]);
    if (tid == 0) dp[0] = 0.0f;
    __syncthreads();

    for (int k = 1; k <= 10; ++k) {
        for (int m = tid; m < 1024; m += 256) {
            if (__popc(m) == k) {
                float best = 3.0e38f;
#pragma unroll
                for (int j = 0; j < 10; ++j) {
                    if (m & (1 << j)) {
                        const float c = dp[m ^ (1 << j)] + cost[(k - 1) * 10 + j];
                        best = fminf(best, c);
                    }
                }
                dp[m] = best;
            }
        }
        __syncthreads();
    }
    if (tid == 0) {
        atomicAdd(out, dp[1023] * (1.0f / ((float)T_ * (float)B_ * (float)S_)));
    }
}

extern "C" void kernel_launch(void* const* d_in, const int* in_sizes, int n_in,
                              void* d_out, int out_size, void* d_ws, size_t ws_size,
                              hipStream_t stream)
{
    const float* pred = (const float*)d_in[0];
    const float* tgt  = (const float*)d_in[1];
    float* partial = (float*)d_ws;          // [64][8][112] floats (~229 KB)
    float* out     = (float*)d_out;

    pit_cost_kernel<<<dim3(NCHUNK, B_), 256, 0, stream>>>(pred, tgt, partial, out);
    pit_dp_kernel<<<B_, 256, 0, stream>>>(partial, out);
}

// Round 2
// 106.952 us; speedup vs baseline: 1.1443x; 1.0120x over previous
//
#include <hip/hip_runtime.h>
#include <hip/hip_bf16.h>

// Problem constants (from reference): B=64, T=8000, S=10.
#define B_ 64
#define T_ 8000
#define S_ 10
#define NCHUNK 8             // T split into 8 chunks of 1000 t's
#define TPC 1000             // t's per chunk
#define QUADS 250            // threads 0..249 each own 4 consecutive t's (160 B)

// ws layout:
//   partial : [B][NCHUNK][112] floats  (110 used: M[100] then D[10])

// ---------------------------------------------------------------------------
// Wave64 sum via DPP (no DS-pipe traffic). Result is valid in lane 63.
// row_shr 1/2/4/8 (lane 15 of each 16-row holds the row total), row_bcast15
// (row_mask 0xa), row_bcast31 (row_mask 0xc) -> lane 63 = full 64-lane sum.
// Each step is one v_add_f32 with a DPP modifier (VALU pipe, no DS traffic).
// ---------------------------------------------------------------------------
__device__ __forceinline__ float wave64_sum_lane63(float x)
{
    int t;
    t = __builtin_amdgcn_update_dpp(0, __float_as_int(x), 0x111, 0xf, 0xf, true); // row_shr:1
    x += __int_as_float(t);
    t = __builtin_amdgcn_update_dpp(0, __float_as_int(x), 0x112, 0xf, 0xf, true); // row_shr:2
    x += __int_as_float(t);
    t = __builtin_amdgcn_update_dpp(0, __float_as_int(x), 0x114, 0xf, 0xf, true); // row_shr:4
    x += __int_as_float(t);
    t = __builtin_amdgcn_update_dpp(0, __float_as_int(x), 0x118, 0xf, 0xf, true); // row_shr:8
    x += __int_as_float(t);
    t = __builtin_amdgcn_update_dpp(0, __float_as_int(x), 0x142, 0xa, 0xf, true); // row_bcast:15
    x += __int_as_float(t);
    t = __builtin_amdgcn_update_dpp(0, __float_as_int(x), 0x143, 0xc, 0xf, true); // row_bcast:31
    x += __int_as_float(t);
    return x;  // lane 63 holds the 64-lane sum
}

// Spread a float4 into 4 statically-indexed slots of a local array.
#define SPR(arr, base, v) \
    arr[(base)] = (v).x; arr[(base)+1] = (v).y; arr[(base)+2] = (v).z; arr[(base)+3] = (v).w;

// Macro-unrolled repetition (indices stay compile-time constants even if the
// compiler would have refused to unroll a 110-trip loop with a call inside —
// the suspected cause of the scratch demotion seen as VGPR_Count=88).
#define RP5(F, b)  F(b) F((b)+1) F((b)+2) F((b)+3) F((b)+4)
#define RP10(F, b) RP5(F, b) RP5(F, (b)+5)

// ---------------------------------------------------------------------------
// Kernel 1: accumulate M[i][j] = sum_t (logp - log1mp)[t,i] * tgt[t,j]
//           and      D[i]     = sum_t log1mp[t,i]
// grid (NCHUNK, B) x 256 threads = 512 blocks = 2 blocks/CU. Thread tid<250
// owns 4 consecutive t's -> 10 contiguous float4 loads per input, all issued
// before any compute. Registers-by-construction: float4 scalars for staging,
// component-wise spreads, macro-unrolled body and epilogue so EVERY array
// index is a literal constant (SROA-proof). Memory-bound goal: 41 MB
// read-once at ~6.3 TB/s ~= 6.5 us.
// Also zeroes out[0] (poisoned 0xAA) so kernel 2 can atomicAdd into it.
// ---------------------------------------------------------------------------
__global__ __launch_bounds__(256, 1) void pit_cost_kernel(
    const float* __restrict__ pred, const float* __restrict__ tgt,
    float* __restrict__ partial, float* __restrict__ out)
{
    const int b     = blockIdx.y;
    const int chunk = blockIdx.x;
    const int tid   = threadIdx.x;

    if (b == 0 && chunk == 0 && tid == 0) out[0] = 0.0f;

    float accM[100];
    float accD[10];
#pragma unroll
    for (int v = 0; v < 100; ++v) accM[v] = 0.0f;
#pragma unroll
    for (int v = 0; v < 10; ++v) accD[v] = 0.0f;

    if (tid < QUADS) {
        const size_t off = (size_t)b * (T_ * S_) + (size_t)chunk * (TPC * S_)
                         + (size_t)tid * 40;
        const float4* P = reinterpret_cast<const float4*>(pred + off);
        const float4* G = reinterpret_cast<const float4*>(tgt + off);

        // Issue all 20 global loads up front (independent, stay in flight).
        const float4 P0 = P[0], P1 = P[1], P2 = P[2], P3 = P[3], P4 = P[4];
        const float4 P5 = P[5], P6 = P[6], P7 = P[7], P8 = P[8], P9 = P[9];
        const float4 G0 = G[0], G1 = G[1], G2 = G[2], G3 = G[3], G4 = G[4];
        const float4 G5 = G[5], G6 = G[6], G7 = G[7], G8 = G[8], G9 = G[9];

        float pr[40];
        float tg[40];
        SPR(pr,  0, P0) SPR(pr,  4, P1) SPR(pr,  8, P2) SPR(pr, 12, P3)
        SPR(pr, 16, P4) SPR(pr, 20, P5) SPR(pr, 24, P6) SPR(pr, 28, P7)
        SPR(pr, 32, P8) SPR(pr, 36, P9)
        SPR(tg,  0, G0) SPR(tg,  4, G1) SPR(tg,  8, G2) SPR(tg, 12, G3)
        SPR(tg, 16, G4) SPR(tg, 20, G5) SPR(tg, 24, G6) SPR(tg, 28, G7)
        SPR(tg, 32, G8) SPR(tg, 36, G9)

#define BODY(u) { \
        float d[10]; \
        _Pragma("unroll") \
        for (int i = 0; i < 10; ++i) { \
            const float pv = pr[(u)*10 + i]; \
            const float lm = __logf(1.0f - pv);   /* log(1-p) */ \
            d[i] = __logf(pv) - lm;               /* logit(p) */ \
            accD[i] += lm; \
        } \
        _Pragma("unroll") \
        for (int i = 0; i < 10; ++i) { \
            _Pragma("unroll") \
            for (int j = 0; j < 10; ++j) { \
                accM[i*10 + j] += d[i] * tg[(u)*10 + j]; \
            } \
        } }

        BODY(0) BODY(1) BODY(2) BODY(3)
#undef BODY
    }

    // Block reduction: per-wave DPP sum (lane 63), then cross-wave sum via LDS.
    __shared__ float red[4][112];
    const int wave = tid >> 6;
    const int lane = tid & 63;

#define REDM(v) { const float x = wave64_sum_lane63(accM[(v)]); \
                  if (lane == 63) red[wave][(v)] = x; }
#define REDD(v) { const float x = wave64_sum_lane63(accD[(v)]); \
                  if (lane == 63) red[wave][100 + (v)] = x; }
    RP10(REDM,  0) RP10(REDM, 10) RP10(REDM, 20) RP10(REDM, 30) RP10(REDM, 40)
    RP10(REDM, 50) RP10(REDM, 60) RP10(REDM, 70) RP10(REDM, 80) RP10(REDM, 90)
    RP10(REDD, 0)
#undef REDM
#undef REDD

    __syncthreads();
    if (tid < 110) {
        const float s = red[0][tid] + red[1][tid] + red[2][tid] + red[3][tid];
        partial[((size_t)b * NCHUNK + chunk) * 112 + tid] = s;
    }
}

// ---------------------------------------------------------------------------
// Kernel 2: per batch b -- finalize cost[i][j] = -(M[i][j] + D[i]) (raw, >0),
// exact min-cost assignment via subset DP over column masks:
//   dp[mask] = min_{j in mask} dp[mask \ j] + cost[popc(mask)-1][j]
// then atomicAdd the normalized optimum into out[0] (zeroed by kernel 1).
// ---------------------------------------------------------------------------
__global__ __launch_bounds__(256, 1) void pit_dp_kernel(
    const float* __restrict__ partial, float* __restrict__ out)
{
    const int b   = blockIdx.x;
    const int tid = threadIdx.x;

    __shared__ float sum[112];
    __shared__ float cost[100];
    __shared__ float dp[1024];

    if (tid < 110) {
        const float* pb = partial + (size_t)b * NCHUNK * 112;
        float s = 0.0f;
#pragma unroll
        for (int c = 0; c < NCHUNK; ++c) s += pb[c * 112 + tid];
        sum[tid] = s;
    }
    __syncthreads();
    if (tid < 100) cost[tid] = -(sum[tid] + sum[100 + tid / 10]);
    if (tid == 0) dp[0] = 0.0f;
    __syncthreads();

    for (int k = 1; k <= 10; ++k) {
        for (int m = tid; m < 1024; m += 256) {
            if (__popc(m) == k) {
                float best = 3.0e38f;
#pragma unroll
                for (int j = 0; j < 10; ++j) {
                    if (m & (1 << j)) {
                        const float c = dp[m ^ (1 << j)] + cost[(k - 1) * 10 + j];
                        best = fminf(best, c);
                    }
                }
                dp[m] = best;
            }
        }
        __syncthreads();
    }
    if (tid == 0) {
        atomicAdd(out, dp[1023] * (1.0f / ((float)T_ * (float)B_ * (float)S_)));
    }
}

extern "C" void kernel_launch(void* const* d_in, const int* in_sizes, int n_in,
                              void* d_out, int out_size, void* d_ws, size_t ws_size,
                              hipStream_t stream)
{
    const float* pred = (const float*)d_in[0];
    const float* tgt  = (const float*)d_in[1];
    float* partial = (float*)d_ws;          // [64][8][112] floats (~229 KB)
    float* out     = (float*)d_out;

    pit_cost_kernel<<<dim3(NCHUNK, B_), 256, 0, stream>>>(pred, tgt, partial, out);
    pit_dp_kernel<<<B_, 256, 0, stream>>>(partial, out);
}